// Round 9
// baseline (242.359 us; speedup 1.0000x reference)
//
#include <hip/hip_runtime.h>
#include <hip/hip_bf16.h>
#include <math.h>

// H2R detector: score map -> 3x3 NMS peaks -> per-batch top-1000 -> ROIs.
// [B=32,1,512,512] fp32 inputs; out = rois[32,1000,5] ++ scores[32,1000]
// ++ valid[32,1000] = 224000 floats.
//
// Scoring replicates numpy's SIMD (Cephes) fp32 expf op-for-op (verified
// bit-exact rounds 5-8: absmax 0.0). DO NOT alter score or emit paths.
//
// Round 9: (a) fused staging loads branchless (clamped slot) so the 10-deep
// float4 batch pipelines; wave-aggregated peak append. (b) selection split
// across CUs: hist (8x32 blocks, LDS hist + sparse packed global merge),
// filter (8x32 blocks, per-block T scan + wave-aggregated append),
// sort_emit (32 blocks, reads only ~1000 candidates). Breaks the
// 1-CU-per-batch streaming bottleneck (per-CU BW ~24 GB/s).

#define B_   32
#define H_   512
#define W_   512
#define HW_  (H_ * W_)
#define K_   1000
#define ROWS_ 16        // interior rows per strip
#define THR_  512       // threads per fused block (8 waves)
#define PBUF_ 2048      // hard max peaks per 16x512 strip
#define PCAP_ 32768     // per-batch peak list capacity (mean ~29.1k)
#define CAND_ 2048      // candidate buffer (power of 2)
#define NBUK_ 4096      // score buckets = bits >> 18 (score < 1.0)
#define NW_   (NBUK_ / 2)   // packed 16-bit words per batch hist
#define SL_   8         // slices per batch for hist/filter

// ---- numpy SIMD (Cephes) fp32 exp replica — bit-exact, do not touch -------
__device__ __forceinline__ float np_expf(float x) {
#pragma clang fp contract(off)
    const float log2e = 1.44269504088896341f;
    float z = x * log2e;
    float m = rintf(z);
    float r = fmaf(m, -0.693359375f, x);
    r = fmaf(m, 2.12194440e-4f, r);
    float r2 = r * r;
    float p = fmaf(1.9875691500e-4f, r, 1.3981999507e-3f);
    p = fmaf(p, r, 8.3334519073e-3f);
    p = fmaf(p, r, 4.1665795894e-2f);
    p = fmaf(p, r, 1.6666665459e-1f);
    p = fmaf(p, r, 5.0000001201e-1f);
    p = fmaf(p, r2, r);
    p = p + 1.0f;
    int mi = (int)m;
    float sc = __int_as_float((127 + mi) << 23);
    return p * sc;
}

__device__ __forceinline__ float sigmoid_np(float x) {
#pragma clang fp contract(off)
    float e = np_expf(-x);
    float d = 1.0f + e;
    return 1.0f / d;
}

__device__ __forceinline__ float score_ref(float r, float u) {
#pragma clang fp contract(off)
    float s  = sigmoid_np(r);
    float s2 = s * s;
    float su = sigmoid_np(u);
    float t  = 0.35f * su;
    float m  = 1.0f - t;
    return s2 * m;
}

__device__ __forceinline__ float sigmoid_fast(float x) {  // box geometry only
    return 1.0f / (1.0f + __expf(-x));
}

// ---- Fused pass: score strip + 3x3 peak test -> per-batch peak list -------
__global__ __launch_bounds__(THR_, 4) void fused_peak_kernel(
    const float* __restrict__ route, const float* __restrict__ unc,
    unsigned long long* __restrict__ plist, int* __restrict__ peak_cnt)
{
    __shared__ float sm[ROWS_ + 2][W_];          // 18x512 = 36.9 KB
    __shared__ unsigned long long pbuf[PBUF_];   // 16 KB
    __shared__ int lcnt, gbase;

    const int tid   = threadIdx.x;
    const int lane  = tid & 63;
    const int strip = blockIdx.x;                // 0..31
    const int b     = blockIdx.y;                // 0..31
    const int r0    = strip * ROWS_;
    if (tid == 0) lcnt = 0;

    const float4* rb4 = (const float4*)(route + (size_t)b * HW_);
    const float4* ub4 = (const float4*)(unc   + (size_t)b * HW_);

    // Stage 18 halo rows: 2304 float4-slots per input. Branchless: slots
    // >= 2304 clamp to 2303 (duplicate same-value LDS writes are benign),
    // so all 10 loads issue back-to-back with no branches between them.
    float4 rv[5], uv[5];
    int lrow[5], c4[5]; bool ok[5];
    #pragma unroll
    for (int k = 0; k < 5; ++k) {
        int slot = tid + k * THR_;
        slot = slot < 2303 ? slot : 2303;
        int row = slot >> 7;
        int gy  = r0 - 1 + row;
        lrow[k] = row; c4[k] = slot & 127;
        ok[k]   = (gy >= 0 && gy < H_);
        int cy  = gy < 0 ? 0 : (gy >= H_ ? H_ - 1 : gy);
        rv[k] = rb4[cy * 128 + c4[k]];
        uv[k] = ub4[cy * 128 + c4[k]];
    }
    #pragma unroll
    for (int k = 0; k < 5; ++k) {
        float4 s;
        s.x = score_ref(rv[k].x, uv[k].x);
        s.y = score_ref(rv[k].y, uv[k].y);
        s.z = score_ref(rv[k].z, uv[k].z);
        s.w = score_ref(rv[k].w, uv[k].w);
        if (!ok[k]) { s.x = -INFINITY; s.y = -INFINITY;
                      s.z = -INFINITY; s.w = -INFINITY; }
        *(float4*)&sm[lrow[k]][c4[k] * 4] = s;
    }
    __syncthreads();

    // Peak test: 16x512 interior, 4-px groups via float4 reads + column max.
    #pragma unroll
    for (int j = 0; j < 4; ++j) {
        int g  = tid + j * THR_;                 // 0..2047
        int ly = 1 + (g >> 7);                   // 1..16
        int x0 = (g & 127) * 4;
        int gy = r0 + (ly - 1);
        float4 q0 = *(const float4*)&sm[ly - 1][x0];
        float4 q1 = *(const float4*)&sm[ly    ][x0];
        float4 q2 = *(const float4*)&sm[ly + 1][x0];
        bool hasL = (x0 > 0), hasR = (x0 + 4 < W_);
        float l0 = hasL ? sm[ly - 1][x0 - 1] : -INFINITY;
        float l1 = hasL ? sm[ly    ][x0 - 1] : -INFINITY;
        float l2 = hasL ? sm[ly + 1][x0 - 1] : -INFINITY;
        float e0 = hasR ? sm[ly - 1][x0 + 4] : -INFINITY;
        float e1 = hasR ? sm[ly    ][x0 + 4] : -INFINITY;
        float e2 = hasR ? sm[ly + 1][x0 + 4] : -INFINITY;
        float f_m1 = fmaxf(l0, fmaxf(l1, l2));
        float f_0  = fmaxf(q0.x, fmaxf(q1.x, q2.x));
        float f_1  = fmaxf(q0.y, fmaxf(q1.y, q2.y));
        float f_2  = fmaxf(q0.z, fmaxf(q1.z, q2.z));
        float f_3  = fmaxf(q0.w, fmaxf(q1.w, q2.w));
        float f_4  = fmaxf(e0, fmaxf(e1, e2));
        float tb0  = fmaxf(q0.x, q2.x);
        float tb1  = fmaxf(q0.y, q2.y);
        float tb2  = fmaxf(q0.z, q2.z);
        float tb3  = fmaxf(q0.w, q2.w);
        float vv[4] = { q1.x, q1.y, q1.z, q1.w };
        float mm[4];
        mm[0] = fmaxf(fmaxf(f_m1, f_1), tb0);
        mm[1] = fmaxf(fmaxf(f_0,  f_2), tb1);
        mm[2] = fmaxf(fmaxf(f_1,  f_3), tb2);
        mm[3] = fmaxf(fmaxf(f_2,  f_4), tb3);
        #pragma unroll
        for (int i = 0; i < 4; ++i) {
            bool take = (vv[i] >= mm[i]);
            unsigned long long mk = __ballot(take);
            if (mk) {
                int ldr = __ffsll((unsigned long long)mk) - 1;
                int base_ = 0;
                if (lane == ldr) base_ = atomicAdd(&lcnt, __popcll(mk));
                base_ = __shfl(base_, ldr, 64);
                if (take) {
                    int p = base_ + __popcll(mk & ((1ull << lane) - 1ull));
                    unsigned int bits = __float_as_uint(vv[i]);
                    unsigned int idx  = (unsigned int)(gy * W_ + x0 + i);
                    if (p < PBUF_)
                        pbuf[p] = ((unsigned long long)bits << 32)
                                  | (0xFFFFFFFFu - idx);
                }
            }
        }
    }
    __syncthreads();
    if (tid == 0) {
        int n = lcnt < PBUF_ ? lcnt : PBUF_;
        gbase = atomicAdd(&peak_cnt[b], n);
    }
    __syncthreads();
    int n = lcnt < PBUF_ ? lcnt : PBUF_;
    int base = gbase;
    for (int i = tid; i < n; i += THR_) {
        int dst = base + i;
        if (dst < PCAP_) plist[(size_t)b * PCAP_ + dst] = pbuf[i];
    }
}

// ---- Hist: 8 slices x 32 batches; LDS hist + sparse packed global merge ---
__global__ __launch_bounds__(256) void hist_kernel(
    const unsigned long long* __restrict__ plist,
    const int* __restrict__ peak_cnt,
    unsigned int* __restrict__ ghist)
{
    __shared__ unsigned int lh[NW_];             // 8 KB, 16-bit packed
    const int s = blockIdx.x, b = blockIdx.y, tid = threadIdx.x;
    for (int i = tid; i < NW_; i += 256) lh[i] = 0u;
    __syncthreads();

    int pc = peak_cnt[b]; if (pc > PCAP_) pc = PCAP_;
    int seg = (pc + SL_ - 1) / SL_;
    int i0 = s * seg, i1 = i0 + seg; if (i1 > pc) i1 = pc;
    const unsigned long long* pl = plist + (size_t)b * PCAP_;
    for (int i = i0 + tid; i < i1; i += 256) {
        unsigned int bkt = ((unsigned int)(pl[i] >> 32)) >> 18;
        atomicAdd(&lh[bkt >> 1], 1u << ((bkt & 1) * 16));
    }
    __syncthreads();
    unsigned int* gh = ghist + b * NW_;
    for (int i = tid; i < NW_; i += 256) {
        unsigned int v = lh[i];
        if (v) atomicAdd(&gh[i], v);   // per-batch totals <= 32768 -> no carry
    }
}

// ---- Filter: per-block T scan, stream slice, append candidates ------------
__global__ __launch_bounds__(256) void filter_kernel(
    const unsigned long long* __restrict__ plist,
    const int* __restrict__ peak_cnt,
    const unsigned int* __restrict__ ghist,
    unsigned long long* __restrict__ cand, int* __restrict__ cand_cnt)
{
    __shared__ unsigned int h[NW_];              // 8 KB
    __shared__ int sh_T;
    const int s = blockIdx.x, b = blockIdx.y, tid = threadIdx.x;
    const int lane = tid & 63, wid = tid >> 6;
    if (tid == 0) sh_T = 0;
    const unsigned int* gh = ghist + b * NW_;
    for (int i = tid; i < NW_; i += 256) h[i] = gh[i];
    __syncthreads();

    // wave0: largest bucket T with count(>=T) >= K (early-exits fast)
    if (wid == 0) {
        int total = 0;
        for (int c = NBUK_ / 64 - 1; c >= 0; --c) {
            int bucket = c * 64 + lane;
            int cnt = (int)((h[bucket >> 1] >> ((bucket & 1) * 16)) & 0xFFFFu);
            int sum = cnt;
            #pragma unroll
            for (int off = 32; off > 0; off >>= 1)
                sum += __shfl_down(sum, off, 64);
            sum = __shfl(sum, 0, 64);
            if (total + sum < K_) { total += sum; continue; }
            int suf = cnt;
            #pragma unroll
            for (int off = 1; off < 64; off <<= 1) {
                int o = __shfl_down(suf, off, 64);
                suf += (lane + off < 64) ? o : 0;
            }
            bool cond = (total + suf) >= K_;
            unsigned long long mask = __ballot(cond);
            int ls = 63 - __builtin_clzll(mask);
            if (lane == 0) sh_T = c * 64 + ls;
            break;
        }
    }
    __syncthreads();
    const unsigned int T = (unsigned int)sh_T;

    int pc = peak_cnt[b]; if (pc > PCAP_) pc = PCAP_;
    int seg = (pc + SL_ - 1) / SL_;
    int i0 = s * seg, i1 = i0 + seg; if (i1 > pc) i1 = pc;
    const unsigned long long* pl = plist + (size_t)b * PCAP_;
    for (int i = i0 + tid; i < i1; i += 256) {
        unsigned long long key = pl[i];
        bool take = ((((unsigned int)(key >> 32)) >> 18) >= T);
        unsigned long long mk = __ballot(take);
        if (mk) {
            int ldr = __ffsll((unsigned long long)mk) - 1;
            int base_ = 0;
            if (lane == ldr) base_ = atomicAdd(&cand_cnt[b], __popcll(mk));
            base_ = __shfl(base_, ldr, 64);
            if (take) {
                int p = base_ + __popcll(mk & ((1ull << lane) - 1ull));
                if (p < CAND_) cand[(size_t)b * CAND_ + p] = key;
            }
        }
    }
}

// ---- Sort + emit: 32 blocks, adaptive 1024/2048 bitonic -------------------
__global__ __launch_bounds__(1024) void sort_emit_kernel(
    const float* __restrict__ scale, const float* __restrict__ unc,
    const unsigned long long* __restrict__ cand,
    const int* __restrict__ cand_cnt,
    const int* __restrict__ ih_p, const int* __restrict__ iw_p,
    float* __restrict__ out)
{
    __shared__ unsigned long long sc_[CAND_];    // 16 KB
    const int b = blockIdx.x, tid = threadIdx.x;

    int nc = cand_cnt[b]; if (nc > CAND_) nc = CAND_;
    int sortN = (nc <= 1024) ? 1024 : CAND_;
    for (int i = tid; i < sortN; i += 1024)
        sc_[i] = (i < nc) ? cand[(size_t)b * CAND_ + i] : 0ull;

    for (int kk = 2; kk <= sortN; kk <<= 1) {
        for (int jj = kk >> 1; jj > 0; jj >>= 1) {
            __syncthreads();
            for (int p = tid; p < (sortN >> 1); p += 1024) {
                int i   = ((p & ~(jj - 1)) << 1) | (p & (jj - 1));
                int ixj = i | jj;
                bool desc = ((i & kk) == 0);
                unsigned long long a = sc_[i], c2 = sc_[ixj];
                if (desc ? (a < c2) : (a > c2)) { sc_[i] = c2; sc_[ixj] = a; }
            }
        }
    }
    __syncthreads();

    const float fih = (float)(*ih_p);
    const float fiw = (float)(*iw_p);
    float* rois   = out;                       // [B,K,5]
    float* scores = out + (size_t)B_ * K_ * 5; // [B,K]
    float* validf = out + (size_t)B_ * K_ * 6; // [B,K]

    for (int k = tid; k < K_; k += 1024) {
        int o = b * K_ + k;
        unsigned long long key = sc_[k];
        unsigned int bits = (unsigned int)(key >> 32);
        if (bits == 0u) {
            rois[o * 5 + 0] = 0.0f; rois[o * 5 + 1] = 0.0f;
            rois[o * 5 + 2] = 0.0f; rois[o * 5 + 3] = 0.0f;
            rois[o * 5 + 4] = 0.0f;
            scores[o] = 0.0f; validf[o] = 0.0f;
        } else {
            float v = __uint_as_float(bits);
            unsigned int idx = 0xFFFFFFFFu - (unsigned int)(key & 0xFFFFFFFFull);
            int y = (int)(idx >> 9), x = (int)(idx & 511u);
            float cx = ((float)x + 0.5f) * 4.0f;
            float cy = ((float)y + 0.5f) * 4.0f;
            float ss = sigmoid_fast(scale[(size_t)b * HW_ + idx]);
            float su = sigmoid_fast(unc  [(size_t)b * HW_ + idx]);
            float side = (32.0f + ss * 480.0f) * (1.0f + 0.25f * su);
            float half = 0.5f * side;
            float x1 = fminf(fmaxf(cx - half, 0.0f), fiw - 1.0f);
            float y1 = fminf(fmaxf(cy - half, 0.0f), fih - 1.0f);
            float x2 = fminf(fmaxf(cx + half, 1.0f), fiw);
            float y2 = fminf(fmaxf(cy + half, 1.0f), fih);
            rois[o * 5 + 0] = (float)b;
            rois[o * 5 + 1] = x1; rois[o * 5 + 2] = y1;
            rois[o * 5 + 3] = x2; rois[o * 5 + 4] = y2;
            scores[o] = v; validf[o] = 1.0f;
        }
    }
}

extern "C" void kernel_launch(void* const* d_in, const int* in_sizes, int n_in,
                              void* d_out, int out_size, void* d_ws, size_t ws_size,
                              hipStream_t stream) {
    const float* route = (const float*)d_in[0];
    const float* scale = (const float*)d_in[1];
    const float* unc   = (const float*)d_in[2];
    const int*   ih    = (const int*)d_in[3];
    const int*   iw    = (const int*)d_in[4];
    float* out = (float*)d_out;

    // ws: [peak_cnt 128B][cand_cnt 128B][pad 256B][ghist 256KB]
    //     [cand 512KB][plist 8MB]
    char* ws = (char*)d_ws;
    int* peak_cnt = (int*)ws;
    int* cand_cnt = (int*)(ws + 128);
    unsigned int* ghist = (unsigned int*)(ws + 512);
    const size_t ghist_b = (size_t)B_ * NW_ * 4;          // 256 KB
    unsigned long long* cand  = (unsigned long long*)(ws + 512 + ghist_b);
    unsigned long long* plist = (unsigned long long*)(ws + 512 + ghist_b
                                                      + (size_t)B_ * CAND_ * 8);

    hipMemsetAsync(d_ws, 0, 512 + ghist_b, stream);

    dim3 g(H_ / ROWS_, B_);   // 32 strips x 32 batches
    fused_peak_kernel<<<g, THR_, 0, stream>>>(route, unc, plist, peak_cnt);
    dim3 gs(SL_, B_);         // 8 slices x 32 batches
    hist_kernel  <<<gs, 256, 0, stream>>>(plist, peak_cnt, ghist);
    filter_kernel<<<gs, 256, 0, stream>>>(plist, peak_cnt, ghist,
                                          cand, cand_cnt);
    sort_emit_kernel<<<B_, 1024, 0, stream>>>(scale, unc, cand, cand_cnt,
                                              ih, iw, out);
}

// Round 10
// 174.547 us; speedup vs baseline: 1.3885x; 1.3885x over previous
//
#include <hip/hip_runtime.h>
#include <hip/hip_bf16.h>
#include <math.h>

// H2R detector: score map -> 3x3 NMS peaks -> per-batch top-1000 -> ROIs.
// [B=32,1,512,512] fp32 inputs; out = rois[32,1000,5] ++ scores[32,1000]
// ++ valid[32,1000] = 224000 floats.
//
// Scoring replicates numpy's SIMD (Cephes) fp32 expf op-for-op (verified
// bit-exact rounds 5-9: absmax 0.0). DO NOT alter score or emit paths.
//
// Round 10: TWO dispatches, no memset. Fused kernel writes peaks into fixed
// per-(batch,strip) segments + plain count stores (no global atomics, no
// zeroed state). Select is the proven r8 single-block-per-batch shape:
// segment counts -> LDS hist -> wave0 T-scan -> gather -> adaptive bitonic
// -> emit. r9's 256-block split regressed (launch overhead ~10us/dispatch,
// latency-bound microblocks); reverted.

#define B_   32
#define H_   512
#define W_   512
#define HW_  (H_ * W_)
#define K_   1000
#define ROWS_ 16            // interior rows per strip
#define THR_  512           // threads per fused block (8 waves)
#define NSTRIP_ 32          // H_/ROWS_
#define SEGCAP_ 1200        // per-strip peak capacity (mean ~900, >10 sigma)
#define CAND_ 2048          // candidate buffer (power of 2)
#define NBUK_ 4096          // score buckets = bits >> 18 (score < 1.0)
#define NW_   (NBUK_ / 2)   // packed 16-bit words

// ---- numpy SIMD (Cephes) fp32 exp replica — bit-exact, do not touch -------
__device__ __forceinline__ float np_expf(float x) {
#pragma clang fp contract(off)
    const float log2e = 1.44269504088896341f;
    float z = x * log2e;
    float m = rintf(z);
    float r = fmaf(m, -0.693359375f, x);
    r = fmaf(m, 2.12194440e-4f, r);
    float r2 = r * r;
    float p = fmaf(1.9875691500e-4f, r, 1.3981999507e-3f);
    p = fmaf(p, r, 8.3334519073e-3f);
    p = fmaf(p, r, 4.1665795894e-2f);
    p = fmaf(p, r, 1.6666665459e-1f);
    p = fmaf(p, r, 5.0000001201e-1f);
    p = fmaf(p, r2, r);
    p = p + 1.0f;
    int mi = (int)m;
    float sc = __int_as_float((127 + mi) << 23);
    return p * sc;
}

__device__ __forceinline__ float sigmoid_np(float x) {
#pragma clang fp contract(off)
    float e = np_expf(-x);
    float d = 1.0f + e;
    return 1.0f / d;
}

__device__ __forceinline__ float score_ref(float r, float u) {
#pragma clang fp contract(off)
    float s  = sigmoid_np(r);
    float s2 = s * s;
    float su = sigmoid_np(u);
    float t  = 0.35f * su;
    float m  = 1.0f - t;
    return s2 * m;
}

__device__ __forceinline__ float sigmoid_fast(float x) {  // box geometry only
    return 1.0f / (1.0f + __expf(-x));
}

// ---- Fused: score strip + 3x3 peak test -> segmented peak list ------------
__global__ __launch_bounds__(THR_, 4) void fused_peak_kernel(
    const float* __restrict__ route, const float* __restrict__ unc,
    unsigned long long* __restrict__ plist, int* __restrict__ pcnt)
{
    __shared__ float sm[ROWS_ + 2][W_];          // 18x512 = 36.9 KB
    __shared__ int lcnt;

    const int tid   = threadIdx.x;
    const int lane  = tid & 63;
    const int strip = blockIdx.x;                // 0..31
    const int b     = blockIdx.y;                // 0..31
    const int r0    = strip * ROWS_;
    if (tid == 0) lcnt = 0;

    const float4* rb4 = (const float4*)(route + (size_t)b * HW_);
    const float4* ub4 = (const float4*)(unc   + (size_t)b * HW_);
    unsigned long long* seg =
        plist + (size_t)(b * NSTRIP_ + strip) * SEGCAP_;

    // Stage 18 halo rows: 2304 float4-slots per input, branchless (slots
    // >= 2304 clamp to 2303; duplicate same-value LDS writes are benign).
    float4 rv[5], uv[5];
    int lrow[5], c4[5]; bool ok[5];
    #pragma unroll
    for (int k = 0; k < 5; ++k) {
        int slot = tid + k * THR_;
        slot = slot < 2303 ? slot : 2303;
        int row = slot >> 7;
        int gy  = r0 - 1 + row;
        lrow[k] = row; c4[k] = slot & 127;
        ok[k]   = (gy >= 0 && gy < H_);
        int cy  = gy < 0 ? 0 : (gy >= H_ ? H_ - 1 : gy);
        rv[k] = rb4[cy * 128 + c4[k]];
        uv[k] = ub4[cy * 128 + c4[k]];
    }
    #pragma unroll
    for (int k = 0; k < 5; ++k) {
        float4 s;
        s.x = score_ref(rv[k].x, uv[k].x);
        s.y = score_ref(rv[k].y, uv[k].y);
        s.z = score_ref(rv[k].z, uv[k].z);
        s.w = score_ref(rv[k].w, uv[k].w);
        if (!ok[k]) { s.x = -INFINITY; s.y = -INFINITY;
                      s.z = -INFINITY; s.w = -INFINITY; }
        *(float4*)&sm[lrow[k]][c4[k] * 4] = s;
    }
    __syncthreads();

    // Peak test: 16x512 interior, 4-px groups via float4 reads + column max;
    // ballot-ranked direct global store into this strip's segment.
    #pragma unroll
    for (int j = 0; j < 4; ++j) {
        int g  = tid + j * THR_;                 // 0..2047
        int ly = 1 + (g >> 7);                   // 1..16
        int x0 = (g & 127) * 4;
        int gy = r0 + (ly - 1);
        float4 q0 = *(const float4*)&sm[ly - 1][x0];
        float4 q1 = *(const float4*)&sm[ly    ][x0];
        float4 q2 = *(const float4*)&sm[ly + 1][x0];
        bool hasL = (x0 > 0), hasR = (x0 + 4 < W_);
        float l0 = hasL ? sm[ly - 1][x0 - 1] : -INFINITY;
        float l1 = hasL ? sm[ly    ][x0 - 1] : -INFINITY;
        float l2 = hasL ? sm[ly + 1][x0 - 1] : -INFINITY;
        float e0 = hasR ? sm[ly - 1][x0 + 4] : -INFINITY;
        float e1 = hasR ? sm[ly    ][x0 + 4] : -INFINITY;
        float e2 = hasR ? sm[ly + 1][x0 + 4] : -INFINITY;
        float f_m1 = fmaxf(l0, fmaxf(l1, l2));
        float f_0  = fmaxf(q0.x, fmaxf(q1.x, q2.x));
        float f_1  = fmaxf(q0.y, fmaxf(q1.y, q2.y));
        float f_2  = fmaxf(q0.z, fmaxf(q1.z, q2.z));
        float f_3  = fmaxf(q0.w, fmaxf(q1.w, q2.w));
        float f_4  = fmaxf(e0, fmaxf(e1, e2));
        float tb0  = fmaxf(q0.x, q2.x);
        float tb1  = fmaxf(q0.y, q2.y);
        float tb2  = fmaxf(q0.z, q2.z);
        float tb3  = fmaxf(q0.w, q2.w);
        float vv[4] = { q1.x, q1.y, q1.z, q1.w };
        float mm[4];
        mm[0] = fmaxf(fmaxf(f_m1, f_1), tb0);
        mm[1] = fmaxf(fmaxf(f_0,  f_2), tb1);
        mm[2] = fmaxf(fmaxf(f_1,  f_3), tb2);
        mm[3] = fmaxf(fmaxf(f_2,  f_4), tb3);
        #pragma unroll
        for (int i = 0; i < 4; ++i) {
            bool take = (vv[i] >= mm[i]);
            unsigned long long mk = __ballot(take);
            if (mk) {
                int ldr = __ffsll((unsigned long long)mk) - 1;
                int base_ = 0;
                if (lane == ldr) base_ = atomicAdd(&lcnt, __popcll(mk));
                base_ = __shfl(base_, ldr, 64);
                if (take) {
                    int p = base_ + __popcll(mk & ((1ull << lane) - 1ull));
                    unsigned int bits = __float_as_uint(vv[i]);
                    unsigned int idx  = (unsigned int)(gy * W_ + x0 + i);
                    if (p < SEGCAP_)
                        seg[p] = ((unsigned long long)bits << 32)
                                 | (0xFFFFFFFFu - idx);
                }
            }
        }
    }
    __syncthreads();
    if (tid == 0) {
        int n = lcnt < SEGCAP_ ? lcnt : SEGCAP_;
        pcnt[b * NSTRIP_ + strip] = n;           // plain store, no init needed
    }
}

// ---- Select: counts -> LDS hist -> wave0 T -> gather -> sort -> emit ------
__global__ __launch_bounds__(1024) void select_kernel(
    const float* __restrict__ scale, const float* __restrict__ unc,
    const unsigned long long* __restrict__ plist,
    const int* __restrict__ pcnt,
    const int* __restrict__ ih_p, const int* __restrict__ iw_p,
    float* __restrict__ out)
{
    __shared__ unsigned int h16[NW_];            // 8 KB packed 16-bit hist
    __shared__ unsigned long long cand[CAND_];   // 16 KB
    __shared__ int scnt[NSTRIP_];
    __shared__ int sh_T, sh_n;

    const int b = blockIdx.x, tid = threadIdx.x;
    const int lane = tid & 63, wid = tid >> 6;
    if (tid == 0) { sh_T = 0; sh_n = 0; }
    if (tid < NSTRIP_) scnt[tid] = pcnt[b * NSTRIP_ + tid];
    for (int i = tid; i < NW_; i += 1024) h16[i] = 0u;
    __syncthreads();

    // Phase 1: histogram all segments (bucket = bits>>18; score < 1.0)
    for (int s = 0; s < NSTRIP_; ++s) {
        int cnt = scnt[s];
        const unsigned long long* sg =
            plist + (size_t)(b * NSTRIP_ + s) * SEGCAP_;
        for (int i = tid; i < cnt; i += 1024) {
            unsigned int bkt = ((unsigned int)(sg[i] >> 32)) >> 18;
            atomicAdd(&h16[bkt >> 1], 1u << ((bkt & 1) * 16));
        }
    }
    __syncthreads();

    // Phase 2 (wave0): largest bucket T with count(>=T) >= K
    if (wid == 0) {
        int total = 0;
        for (int c = NBUK_ / 64 - 1; c >= 0; --c) {
            int bucket = c * 64 + lane;
            int cnt = (int)((h16[bucket >> 1] >> ((bucket & 1) * 16)) & 0xFFFFu);
            int sum = cnt;
            #pragma unroll
            for (int off = 32; off > 0; off >>= 1)
                sum += __shfl_down(sum, off, 64);
            sum = __shfl(sum, 0, 64);
            if (total + sum < K_) { total += sum; continue; }
            int suf = cnt;
            #pragma unroll
            for (int off = 1; off < 64; off <<= 1) {
                int o = __shfl_down(suf, off, 64);
                suf += (lane + off < 64) ? o : 0;
            }
            bool cond = (total + suf) >= K_;
            unsigned long long mask = __ballot(cond);
            int ls = 63 - __builtin_clzll(mask);
            if (lane == 0) sh_T = c * 64 + ls;
            break;
        }
    }
    __syncthreads();
    const unsigned int T = (unsigned int)sh_T;

    // Phase 3: gather candidates with bucket >= T
    for (int s = 0; s < NSTRIP_; ++s) {
        int cnt = scnt[s];
        const unsigned long long* sg =
            plist + (size_t)(b * NSTRIP_ + s) * SEGCAP_;
        for (int i = tid; i < cnt; i += 1024) {
            unsigned long long key = sg[i];
            if (((((unsigned int)(key >> 32))) >> 18) >= T) {
                int p = atomicAdd(&sh_n, 1);
                if (p < CAND_) cand[p] = key;
            }
        }
    }
    __syncthreads();
    int nc = sh_n; if (nc > CAND_) nc = CAND_;
    int sortN = (nc <= 1024) ? 1024 : CAND_;
    for (int i = tid; i < sortN; i += 1024)
        if (i >= nc) cand[i] = 0ull;

    // Phase 4: pair-indexed bitonic sort (desc, exact 64-bit key)
    for (int kk = 2; kk <= sortN; kk <<= 1) {
        for (int jj = kk >> 1; jj > 0; jj >>= 1) {
            __syncthreads();
            for (int p = tid; p < (sortN >> 1); p += 1024) {
                int i   = ((p & ~(jj - 1)) << 1) | (p & (jj - 1));
                int ixj = i | jj;
                bool desc = ((i & kk) == 0);
                unsigned long long a = cand[i], c2 = cand[ixj];
                if (desc ? (a < c2) : (a > c2)) { cand[i] = c2; cand[ixj] = a; }
            }
        }
    }
    __syncthreads();

    // Phase 5: emit top-K (verified path — do not touch)
    const float fih = (float)(*ih_p);
    const float fiw = (float)(*iw_p);
    float* rois   = out;                       // [B,K,5]
    float* scores = out + (size_t)B_ * K_ * 5; // [B,K]
    float* validf = out + (size_t)B_ * K_ * 6; // [B,K]

    for (int k = tid; k < K_; k += 1024) {
        int o = b * K_ + k;
        unsigned long long key = cand[k];
        unsigned int bits = (unsigned int)(key >> 32);
        if (bits == 0u) {
            rois[o * 5 + 0] = 0.0f; rois[o * 5 + 1] = 0.0f;
            rois[o * 5 + 2] = 0.0f; rois[o * 5 + 3] = 0.0f;
            rois[o * 5 + 4] = 0.0f;
            scores[o] = 0.0f; validf[o] = 0.0f;
        } else {
            float v = __uint_as_float(bits);
            unsigned int idx = 0xFFFFFFFFu - (unsigned int)(key & 0xFFFFFFFFull);
            int y = (int)(idx >> 9), x = (int)(idx & 511u);
            float cx = ((float)x + 0.5f) * 4.0f;
            float cy = ((float)y + 0.5f) * 4.0f;
            float ss = sigmoid_fast(scale[(size_t)b * HW_ + idx]);
            float su = sigmoid_fast(unc  [(size_t)b * HW_ + idx]);
            float side = (32.0f + ss * 480.0f) * (1.0f + 0.25f * su);
            float half = 0.5f * side;
            float x1 = fminf(fmaxf(cx - half, 0.0f), fiw - 1.0f);
            float y1 = fminf(fmaxf(cy - half, 0.0f), fih - 1.0f);
            float x2 = fminf(fmaxf(cx + half, 1.0f), fiw);
            float y2 = fminf(fmaxf(cy + half, 1.0f), fih);
            rois[o * 5 + 0] = (float)b;
            rois[o * 5 + 1] = x1; rois[o * 5 + 2] = y1;
            rois[o * 5 + 3] = x2; rois[o * 5 + 4] = y2;
            scores[o] = v; validf[o] = 1.0f;
        }
    }
}

extern "C" void kernel_launch(void* const* d_in, const int* in_sizes, int n_in,
                              void* d_out, int out_size, void* d_ws, size_t ws_size,
                              hipStream_t stream) {
    const float* route = (const float*)d_in[0];
    const float* scale = (const float*)d_in[1];
    const float* unc   = (const float*)d_in[2];
    const int*   ih    = (const int*)d_in[3];
    const int*   iw    = (const int*)d_in[4];
    float* out = (float*)d_out;

    // ws: [pcnt 4KB][plist 32*32*1200*8 = 9.83MB]; every slot we read is
    // freshly written each launch -> no zeroing, no memset dispatch.
    char* ws = (char*)d_ws;
    int* pcnt = (int*)ws;
    unsigned long long* plist = (unsigned long long*)(ws + 4096);

    dim3 g(NSTRIP_, B_);      // 32 strips x 32 batches
    fused_peak_kernel<<<g, THR_, 0, stream>>>(route, unc, plist, pcnt);
    select_kernel<<<B_, 1024, 0, stream>>>(scale, unc, plist, pcnt,
                                           ih, iw, out);
}

// Round 11
// 163.410 us; speedup vs baseline: 1.4831x; 1.0682x over previous
//
#include <hip/hip_runtime.h>
#include <hip/hip_bf16.h>
#include <math.h>

// H2R detector: score map -> 3x3 NMS peaks -> per-batch top-1000 -> ROIs.
// [B=32,1,512,512] fp32 inputs; out = rois[32,1000,5] ++ scores[32,1000]
// ++ valid[32,1000] = 224000 floats.
//
// Scoring replicates numpy's SIMD (Cephes) fp32 expf op-for-op (verified
// bit-exact rounds 5-10: absmax 0.0). DO NOT alter score or emit paths.
//
// Round 11: select restructured for memory-level parallelism. Fused kernel
// zero-fills segment tails so select streams the whole per-batch region
// flat (ulonglong2 x2-unrolled, no per-segment masking); 4 sub-histograms
// (per wave-quad) cut LDS atomic same-word contention 4x; gather appends
// via wave-ballot aggregation (1 atomic/wave). pcnt buffer dropped.

#define B_   32
#define H_   512
#define W_   512
#define HW_  (H_ * W_)
#define K_   1000
#define ROWS_ 16            // interior rows per strip
#define THR_  512           // threads per fused block (8 waves)
#define NSTRIP_ 32          // H_/ROWS_
#define SEGCAP_ 1200        // per-strip peak capacity (mean ~900; even -> 16B seg align)
#define NSLOT_ (NSTRIP_ * SEGCAP_)   // 38400 slots per batch
#define NPAIR_ (NSLOT_ / 2)          // 19200 ulonglong2 pairs
#define CAND_ 2048          // candidate buffer (power of 2)
#define NBUK_ 4096          // score buckets = bits >> 18 (score < 1.0)
#define NW_   (NBUK_ / 2)   // packed 16-bit words per hist

// ---- numpy SIMD (Cephes) fp32 exp replica — bit-exact, do not touch -------
__device__ __forceinline__ float np_expf(float x) {
#pragma clang fp contract(off)
    const float log2e = 1.44269504088896341f;
    float z = x * log2e;
    float m = rintf(z);
    float r = fmaf(m, -0.693359375f, x);
    r = fmaf(m, 2.12194440e-4f, r);
    float r2 = r * r;
    float p = fmaf(1.9875691500e-4f, r, 1.3981999507e-3f);
    p = fmaf(p, r, 8.3334519073e-3f);
    p = fmaf(p, r, 4.1665795894e-2f);
    p = fmaf(p, r, 1.6666665459e-1f);
    p = fmaf(p, r, 5.0000001201e-1f);
    p = fmaf(p, r2, r);
    p = p + 1.0f;
    int mi = (int)m;
    float sc = __int_as_float((127 + mi) << 23);
    return p * sc;
}

__device__ __forceinline__ float sigmoid_np(float x) {
#pragma clang fp contract(off)
    float e = np_expf(-x);
    float d = 1.0f + e;
    return 1.0f / d;
}

__device__ __forceinline__ float score_ref(float r, float u) {
#pragma clang fp contract(off)
    float s  = sigmoid_np(r);
    float s2 = s * s;
    float su = sigmoid_np(u);
    float t  = 0.35f * su;
    float m  = 1.0f - t;
    return s2 * m;
}

__device__ __forceinline__ float sigmoid_fast(float x) {  // box geometry only
    return 1.0f / (1.0f + __expf(-x));
}

// ---- Fused: score strip + 3x3 peak test -> zero-padded segment ------------
__global__ __launch_bounds__(THR_, 4) void fused_peak_kernel(
    const float* __restrict__ route, const float* __restrict__ unc,
    unsigned long long* __restrict__ plist)
{
    __shared__ float sm[ROWS_ + 2][W_];          // 18x512 = 36.9 KB
    __shared__ int lcnt;

    const int tid   = threadIdx.x;
    const int lane  = tid & 63;
    const int strip = blockIdx.x;                // 0..31
    const int b     = blockIdx.y;                // 0..31
    const int r0    = strip * ROWS_;
    if (tid == 0) lcnt = 0;

    const float4* rb4 = (const float4*)(route + (size_t)b * HW_);
    const float4* ub4 = (const float4*)(unc   + (size_t)b * HW_);
    unsigned long long* seg =
        plist + (size_t)(b * NSTRIP_ + strip) * SEGCAP_;

    // Stage 18 halo rows: branchless (slot clamp), 10 loads in flight.
    float4 rv[5], uv[5];
    int lrow[5], c4[5]; bool ok[5];
    #pragma unroll
    for (int k = 0; k < 5; ++k) {
        int slot = tid + k * THR_;
        slot = slot < 2303 ? slot : 2303;
        int row = slot >> 7;
        int gy  = r0 - 1 + row;
        lrow[k] = row; c4[k] = slot & 127;
        ok[k]   = (gy >= 0 && gy < H_);
        int cy  = gy < 0 ? 0 : (gy >= H_ ? H_ - 1 : gy);
        rv[k] = rb4[cy * 128 + c4[k]];
        uv[k] = ub4[cy * 128 + c4[k]];
    }
    #pragma unroll
    for (int k = 0; k < 5; ++k) {
        float4 s;
        s.x = score_ref(rv[k].x, uv[k].x);
        s.y = score_ref(rv[k].y, uv[k].y);
        s.z = score_ref(rv[k].z, uv[k].z);
        s.w = score_ref(rv[k].w, uv[k].w);
        if (!ok[k]) { s.x = -INFINITY; s.y = -INFINITY;
                      s.z = -INFINITY; s.w = -INFINITY; }
        *(float4*)&sm[lrow[k]][c4[k] * 4] = s;
    }
    __syncthreads();

    // Peak test: 16x512 interior, 4-px groups, float4 reads + column max.
    #pragma unroll
    for (int j = 0; j < 4; ++j) {
        int g  = tid + j * THR_;                 // 0..2047
        int ly = 1 + (g >> 7);                   // 1..16
        int x0 = (g & 127) * 4;
        int gy = r0 + (ly - 1);
        float4 q0 = *(const float4*)&sm[ly - 1][x0];
        float4 q1 = *(const float4*)&sm[ly    ][x0];
        float4 q2 = *(const float4*)&sm[ly + 1][x0];
        bool hasL = (x0 > 0), hasR = (x0 + 4 < W_);
        float l0 = hasL ? sm[ly - 1][x0 - 1] : -INFINITY;
        float l1 = hasL ? sm[ly    ][x0 - 1] : -INFINITY;
        float l2 = hasL ? sm[ly + 1][x0 - 1] : -INFINITY;
        float e0 = hasR ? sm[ly - 1][x0 + 4] : -INFINITY;
        float e1 = hasR ? sm[ly    ][x0 + 4] : -INFINITY;
        float e2 = hasR ? sm[ly + 1][x0 + 4] : -INFINITY;
        float f_m1 = fmaxf(l0, fmaxf(l1, l2));
        float f_0  = fmaxf(q0.x, fmaxf(q1.x, q2.x));
        float f_1  = fmaxf(q0.y, fmaxf(q1.y, q2.y));
        float f_2  = fmaxf(q0.z, fmaxf(q1.z, q2.z));
        float f_3  = fmaxf(q0.w, fmaxf(q1.w, q2.w));
        float f_4  = fmaxf(e0, fmaxf(e1, e2));
        float tb0  = fmaxf(q0.x, q2.x);
        float tb1  = fmaxf(q0.y, q2.y);
        float tb2  = fmaxf(q0.z, q2.z);
        float tb3  = fmaxf(q0.w, q2.w);
        float vv[4] = { q1.x, q1.y, q1.z, q1.w };
        float mm[4];
        mm[0] = fmaxf(fmaxf(f_m1, f_1), tb0);
        mm[1] = fmaxf(fmaxf(f_0,  f_2), tb1);
        mm[2] = fmaxf(fmaxf(f_1,  f_3), tb2);
        mm[3] = fmaxf(fmaxf(f_2,  f_4), tb3);
        #pragma unroll
        for (int i = 0; i < 4; ++i) {
            bool take = (vv[i] >= mm[i]);
            unsigned long long mk = __ballot(take);
            if (mk) {
                int ldr = __ffsll((unsigned long long)mk) - 1;
                int base_ = 0;
                if (lane == ldr) base_ = atomicAdd(&lcnt, __popcll(mk));
                base_ = __shfl(base_, ldr, 64);
                if (take) {
                    int p = base_ + __popcll(mk & ((1ull << lane) - 1ull));
                    unsigned int bits = __float_as_uint(vv[i]);
                    unsigned int idx  = (unsigned int)(gy * W_ + x0 + i);
                    if (p < SEGCAP_)
                        seg[p] = ((unsigned long long)bits << 32)
                                 | (0xFFFFFFFFu - idx);
                }
            }
        }
    }
    __syncthreads();
    // Zero-fill the tail so select can stream the region unconditionally.
    int n = lcnt < SEGCAP_ ? lcnt : SEGCAP_;
    for (int i = n + tid; i < SEGCAP_; i += THR_) seg[i] = 0ull;
}

// ---- Select: flat stream -> 4x sub-hist -> wave0 T -> gather -> sort ------
__global__ __launch_bounds__(1024) void select_kernel(
    const float* __restrict__ scale, const float* __restrict__ unc,
    const unsigned long long* __restrict__ plist,
    const int* __restrict__ ih_p, const int* __restrict__ iw_p,
    float* __restrict__ out)
{
    __shared__ unsigned int h4[4 * NW_];         // 32 KB: 4 sub-hists
    __shared__ unsigned long long cand[CAND_];   // 16 KB
    __shared__ int sh_T, sh_n;

    const int b = blockIdx.x, tid = threadIdx.x;
    const int lane = tid & 63, wid = tid >> 6;
    if (tid == 0) { sh_T = 0; sh_n = 0; }
    for (int i = tid; i < 4 * NW_; i += 1024) h4[i] = 0u;
    __syncthreads();

    const ulonglong2* p2 =
        (const ulonglong2*)(plist + (size_t)b * NSLOT_);
    unsigned int* hw = h4 + (wid >> 2) * NW_;    // wave-quad private hist

    // Phase 1: flat vectorized histogram (zero keys -> bkt 0, skipped)
    {
        int i = tid;
        for (; i + 1024 < NPAIR_; i += 2048) {
            ulonglong2 a = p2[i];
            ulonglong2 c = p2[i + 1024];
            unsigned int b0 = ((unsigned int)(a.x >> 32)) >> 18;
            unsigned int b1 = ((unsigned int)(a.y >> 32)) >> 18;
            unsigned int b2 = ((unsigned int)(c.x >> 32)) >> 18;
            unsigned int b3 = ((unsigned int)(c.y >> 32)) >> 18;
            if (b0) atomicAdd(&hw[b0 >> 1], 1u << ((b0 & 1) * 16));
            if (b1) atomicAdd(&hw[b1 >> 1], 1u << ((b1 & 1) * 16));
            if (b2) atomicAdd(&hw[b2 >> 1], 1u << ((b2 & 1) * 16));
            if (b3) atomicAdd(&hw[b3 >> 1], 1u << ((b3 & 1) * 16));
        }
        for (; i < NPAIR_; i += 1024) {
            ulonglong2 a = p2[i];
            unsigned int b0 = ((unsigned int)(a.x >> 32)) >> 18;
            unsigned int b1 = ((unsigned int)(a.y >> 32)) >> 18;
            if (b0) atomicAdd(&hw[b0 >> 1], 1u << ((b0 & 1) * 16));
            if (b1) atomicAdd(&hw[b1 >> 1], 1u << ((b1 & 1) * 16));
        }
    }
    __syncthreads();
    // merge sub-hists into h4[0..NW_)
    for (int i = tid; i < NW_; i += 1024)
        h4[i] = h4[i] + h4[NW_ + i] + h4[2 * NW_ + i] + h4[3 * NW_ + i];
    __syncthreads();

    // Phase 2 (wave0): largest bucket T with count(>=T) >= K
    if (wid == 0) {
        int total = 0;
        for (int c = NBUK_ / 64 - 1; c >= 0; --c) {
            int bucket = c * 64 + lane;
            int cnt = (int)((h4[bucket >> 1] >> ((bucket & 1) * 16)) & 0xFFFFu);
            int sum = cnt;
            #pragma unroll
            for (int off = 32; off > 0; off >>= 1)
                sum += __shfl_down(sum, off, 64);
            sum = __shfl(sum, 0, 64);
            if (total + sum < K_) { total += sum; continue; }
            int suf = cnt;
            #pragma unroll
            for (int off = 1; off < 64; off <<= 1) {
                int o = __shfl_down(suf, off, 64);
                suf += (lane + off < 64) ? o : 0;
            }
            bool cond = (total + suf) >= K_;
            unsigned long long mask = __ballot(cond);
            int ls = 63 - __builtin_clzll(mask);
            if (lane == 0) sh_T = c * 64 + ls;
            break;
        }
    }
    __syncthreads();
    const unsigned int T = (unsigned int)sh_T;

    // Phase 3: flat vectorized gather, wave-ballot aggregated append
    {
        int i = tid;
        for (; i + 1024 < NPAIR_; i += 2048) {
            ulonglong2 a = p2[i];
            ulonglong2 c = p2[i + 1024];
            unsigned long long ks[4] = { a.x, a.y, c.x, c.y };
            #pragma unroll
            for (int q = 0; q < 4; ++q) {
                bool take = ((((unsigned int)(ks[q] >> 32))) >> 18) >= T;
                unsigned long long mk = __ballot(take);
                if (mk) {
                    int ldr = __ffsll((unsigned long long)mk) - 1;
                    int base_ = 0;
                    if (lane == ldr) base_ = atomicAdd(&sh_n, __popcll(mk));
                    base_ = __shfl(base_, ldr, 64);
                    if (take) {
                        int p = base_ + __popcll(mk & ((1ull << lane) - 1ull));
                        if (p < CAND_) cand[p] = ks[q];
                    }
                }
            }
        }
        for (; i < NPAIR_; i += 1024) {
            ulonglong2 a = p2[i];
            unsigned long long ks[2] = { a.x, a.y };
            #pragma unroll
            for (int q = 0; q < 2; ++q) {
                bool take = ((((unsigned int)(ks[q] >> 32))) >> 18) >= T;
                unsigned long long mk = __ballot(take);
                if (mk) {
                    int ldr = __ffsll((unsigned long long)mk) - 1;
                    int base_ = 0;
                    if (lane == ldr) base_ = atomicAdd(&sh_n, __popcll(mk));
                    base_ = __shfl(base_, ldr, 64);
                    if (take) {
                        int p = base_ + __popcll(mk & ((1ull << lane) - 1ull));
                        if (p < CAND_) cand[p] = ks[q];
                    }
                }
            }
        }
    }
    __syncthreads();
    int nc = sh_n; if (nc > CAND_) nc = CAND_;
    int sortN = (nc <= 1024) ? 1024 : CAND_;
    for (int i = tid; i < sortN; i += 1024)
        if (i >= nc) cand[i] = 0ull;

    // Phase 4: pair-indexed bitonic sort (desc, exact 64-bit key)
    for (int kk = 2; kk <= sortN; kk <<= 1) {
        for (int jj = kk >> 1; jj > 0; jj >>= 1) {
            __syncthreads();
            for (int p = tid; p < (sortN >> 1); p += 1024) {
                int i   = ((p & ~(jj - 1)) << 1) | (p & (jj - 1));
                int ixj = i | jj;
                bool desc = ((i & kk) == 0);
                unsigned long long a = cand[i], c2 = cand[ixj];
                if (desc ? (a < c2) : (a > c2)) { cand[i] = c2; cand[ixj] = a; }
            }
        }
    }
    __syncthreads();

    // Phase 5: emit top-K (verified path — do not touch)
    const float fih = (float)(*ih_p);
    const float fiw = (float)(*iw_p);
    float* rois   = out;                       // [B,K,5]
    float* scores = out + (size_t)B_ * K_ * 5; // [B,K]
    float* validf = out + (size_t)B_ * K_ * 6; // [B,K]

    for (int k = tid; k < K_; k += 1024) {
        int o = b * K_ + k;
        unsigned long long key = cand[k];
        unsigned int bits = (unsigned int)(key >> 32);
        if (bits == 0u) {
            rois[o * 5 + 0] = 0.0f; rois[o * 5 + 1] = 0.0f;
            rois[o * 5 + 2] = 0.0f; rois[o * 5 + 3] = 0.0f;
            rois[o * 5 + 4] = 0.0f;
            scores[o] = 0.0f; validf[o] = 0.0f;
        } else {
            float v = __uint_as_float(bits);
            unsigned int idx = 0xFFFFFFFFu - (unsigned int)(key & 0xFFFFFFFFull);
            int y = (int)(idx >> 9), x = (int)(idx & 511u);
            float cx = ((float)x + 0.5f) * 4.0f;
            float cy = ((float)y + 0.5f) * 4.0f;
            float ss = sigmoid_fast(scale[(size_t)b * HW_ + idx]);
            float su = sigmoid_fast(unc  [(size_t)b * HW_ + idx]);
            float side = (32.0f + ss * 480.0f) * (1.0f + 0.25f * su);
            float half = 0.5f * side;
            float x1 = fminf(fmaxf(cx - half, 0.0f), fiw - 1.0f);
            float y1 = fminf(fmaxf(cy - half, 0.0f), fih - 1.0f);
            float x2 = fminf(fmaxf(cx + half, 1.0f), fiw);
            float y2 = fminf(fmaxf(cy + half, 1.0f), fih);
            rois[o * 5 + 0] = (float)b;
            rois[o * 5 + 1] = x1; rois[o * 5 + 2] = y1;
            rois[o * 5 + 3] = x2; rois[o * 5 + 4] = y2;
            scores[o] = v; validf[o] = 1.0f;
        }
    }
}

extern "C" void kernel_launch(void* const* d_in, const int* in_sizes, int n_in,
                              void* d_out, int out_size, void* d_ws, size_t ws_size,
                              hipStream_t stream) {
    const float* route = (const float*)d_in[0];
    const float* scale = (const float*)d_in[1];
    const float* unc   = (const float*)d_in[2];
    const int*   ih    = (const int*)d_in[3];
    const int*   iw    = (const int*)d_in[4];
    float* out = (float*)d_out;

    // ws: [plist 32*38400*8 = 9.83MB]; every slot read by select is freshly
    // written (peaks + zero fill) each launch -> no zeroing dispatch.
    unsigned long long* plist = (unsigned long long*)d_ws;

    dim3 g(NSTRIP_, B_);      // 32 strips x 32 batches
    fused_peak_kernel<<<g, THR_, 0, stream>>>(route, unc, plist);
    select_kernel<<<B_, 1024, 0, stream>>>(scale, unc, plist, ih, iw, out);
}